// Round 15
// baseline (277.440 us; speedup 1.0000x reference)
//
#include <hip/hip_runtime.h>

#define T      1024
#define DFEAT  80
#define NF4    20       // DFEAT / 4
#define MARGIN 40.0f    // W^2 = d0^2 + MARGIN*sigma^2 -> tail cut at e^-20
#define PAD_B0 16       // index slop for b0's bucket-sorted centers
#define PAD_BN 2        // safety slop for exactly-sorted b>=1

// ---------------------------------------------------------------------------
// prep: one WAVE per batch. f64 shuffle-scan cumsum. Emits value-sorted
// centers cls + permutation perm + exact f32 cmax[b].
// b>=1: rotation [c1..c1023, c0] is exactly ascending.
// b==0: ref zeroes cs row -> c = d/2 in [0,0.5); single-wave counting sort
// (within-bucket disorder absorbed by PAD_B0 in align).   [proven r8/r11/r13]
// ---------------------------------------------------------------------------
__global__ __launch_bounds__(64) void prep_kernel(
    const float* __restrict__ d, float* __restrict__ cls,
    unsigned short* __restrict__ perm, float* __restrict__ cmax)
{
    __shared__ int hist[T];
    const int b = blockIdx.x, lane = threadIdx.x;

    const float4* dr4 = (const float4*)(d + (size_t)b * T) + lane * 4;
    float4 a0 = dr4[0], a1 = dr4[1], a2 = dr4[2], a3 = dr4[3];
    float loc[16] = {a0.x,a0.y,a0.z,a0.w, a1.x,a1.y,a1.z,a1.w,
                     a2.x,a2.y,a2.z,a2.w, a3.x,a3.y,a3.z,a3.w};
    double pre[17];
    pre[0] = 0.0;
    #pragma unroll
    for (int i = 0; i < 16; ++i) pre[i + 1] = pre[i] + (double)loc[i];
    const double lsum = pre[16];
    double x = lsum;
    #pragma unroll
    for (int off = 1; off < 64; off <<= 1) {
        double y = __shfl_up(x, off);
        if (lane >= off) x += y;
    }
    const double exclb = x - lsum;        // sum over lanes < lane
    const double total = __shfl(x, 63);

    float val[16];
    #pragma unroll
    for (int i = 0; i < 16; ++i) {
        const int t = lane * 16 + i;
        double cs;
        if (b == 0)      cs = 0.0;        // ref quirk: whole batch-0 row
        else if (t == 0) cs = total;      // roll wraps row total to t=0
        else             cs = exclb + pre[i];
        val[i] = (float)((double)loc[i] * 0.5 + cs);
    }

    if (b > 0) {
        #pragma unroll
        for (int i = 0; i < 16; ++i) {
            const int t = lane * 16 + i;
            const int j = (t == 0) ? (T - 1) : (t - 1);   // rotation = sorted
            cls[b * T + j]  = val[i];
            perm[b * T + j] = (unsigned short)t;
        }
        if (lane == 0) cmax[b] = val[0];                  // t=0 is global max
    } else {
        float mn = val[0], mx = val[0];
        #pragma unroll
        for (int i = 1; i < 16; ++i) { mn = fminf(mn, val[i]); mx = fmaxf(mx, val[i]); }
        #pragma unroll
        for (int off = 32; off > 0; off >>= 1) {
            mn = fminf(mn, __shfl_xor(mn, off));
            mx = fmaxf(mx, __shfl_xor(mx, off));
        }
        if (lane == 0) cmax[0] = mx;
        const float scale = 1023.0f / fmaxf(mx - mn, 1e-20f);
        int bkt[16];
        #pragma unroll
        for (int i = 0; i < 16; ++i)
            bkt[i] = min(1023, max(0, (int)((val[i] - mn) * scale)));
        for (int i = lane; i < T; i += 64) hist[i] = 0;
        __syncthreads();                   // single wave: cheap
        #pragma unroll
        for (int i = 0; i < 16; ++i) atomicAdd(&hist[bkt[i]], 1);
        __syncthreads();
        int hp[17];
        hp[0] = 0;
        #pragma unroll
        for (int i = 0; i < 16; ++i) hp[i + 1] = hp[i] + hist[lane * 16 + i];
        const int hl = hp[16];
        int xs = hl;
        #pragma unroll
        for (int off = 1; off < 64; off <<= 1) {
            int ys = __shfl_up(xs, off);
            if (lane >= off) xs += ys;
        }
        const int base = xs - hl;          // exclusive over lanes
        __syncthreads();
        #pragma unroll
        for (int i = 0; i < 16; ++i) hist[lane * 16 + i] = base + hp[i];
        __syncthreads();
        #pragma unroll
        for (int i = 0; i < 16; ++i) {
            const int pos = atomicAdd(&hist[bkt[i]], 1);
            cls[pos]  = val[i];
            perm[pos] = (unsigned short)(lane * 16 + i);
        }
    }
}

// first index j in [0, T) with a[j] >= x ; returns T if none
__device__ __forceinline__ int lbg(const float* __restrict__ a, float x) {
    int base = 0, len = T;
    while (len > 0) {
        int half = len >> 1;
        if (a[base + half] < x) { base += half + 1; len -= half + 1; }
        else len = half;
    }
    return base;
}

// ---------------------------------------------------------------------------
// align: ONE WAVE per (b,s). j split 16-way (jp) x features 4-way (q, 5
// float4/lane). __launch_bounds__(256,4): 4 waves/EU min => <=128 VGPRs —
// round-13 lesson: without it hipcc capped at 32 VGPRs and SPILLED acc[5]
// to scratch (426 MB HBM writes, 20x amplification, 220 us).
// Weights in REFERENCE f32 op order: v = -(dd*dd)/tss, w = __expf(v - v0),
// v0 = -(d0*d0)/tss, exact f32 d0.   (round-4 lesson)
// ---------------------------------------------------------------------------
__global__ __launch_bounds__(256, 4) void align_kernel(
    const float* __restrict__ h, const float* __restrict__ cls,
    const unsigned short* __restrict__ perm, const float* __restrict__ cmax,
    const float* __restrict__ sigma, float* __restrict__ u, int size)
{
    const int wv   = (blockIdx.x << 2) | (threadIdx.x >> 6);  // slin = b*size+s
    const int lane = threadIdx.x & 63;
    const int jp   = lane & 15;          // j-parallel lane
    const int q    = lane >> 4;          // feature quad: float4 idx q + 4*i5
    const int b    = wv / size;
    const int s    = wv - b * size;

    const float sg  = sigma[0];
    const float tss = 2.0f * sg * sg;
    const float ts  = (float)s + 1.5f;

    const float* a = cls + (size_t)b * T;

    // window (all lanes redundantly; identical addresses -> broadcast loads)
    float d0; int pad;
    if (b == 0) {
        d0 = fabsf(ts - cmax[0]);        // ts > all centers -> nearest = cmax
        pad = PAD_B0;
    } else {
        const int ins = lbg(a, ts);
        d0 = 1e30f;
        if (ins < T) d0 = fminf(d0, fabsf(a[ins] - ts));
        if (ins > 0) d0 = fminf(d0, fabsf(ts - a[ins - 1]));
        pad = PAD_BN;
    }
    const float Ws  = sqrtf(fmaf(sg * sg, MARGIN, d0 * d0));
    const int   jlo = max(0, lbg(a, ts - Ws) - pad);
    const int   jhi = min(T, lbg(a, ts + Ws) + pad);
    const float v0  = -(d0 * d0) / tss;  // f32 max score, ref rounding

    const unsigned short* pb = perm + (size_t)b * T;
    const float4* hb4 = (const float4*)(h + (size_t)b * T * DFEAT);

    float4 acc[5];
    #pragma unroll
    for (int i5 = 0; i5 < 5; ++i5) acc[i5] = make_float4(0.f, 0.f, 0.f, 0.f);
    float ls = 0.f;

    for (int j = jlo + jp; j < jhi; j += 16) {
        const float cv = a[j];
        const float dd = ts - cv;
        const float v  = -(dd * dd) / tss;           // ref op order
        const float w  = __expf(v - v0);
        ls += w;
        const int row = pb[j];
        const float4* hr = hb4 + (size_t)row * NF4 + q;
        #pragma unroll
        for (int i5 = 0; i5 < 5; ++i5) {
            const float4 hv = hr[4 * i5];
            acc[i5].x += w * hv.x; acc[i5].y += w * hv.y;
            acc[i5].z += w * hv.z; acc[i5].w += w * hv.w;
        }
    }

    // reduce over the 16 jp lanes (xor 1,2,4,8 stays within the q-group)
    #pragma unroll
    for (int o = 1; o <= 8; o <<= 1) {
        ls += __shfl_xor(ls, o);
        #pragma unroll
        for (int i5 = 0; i5 < 5; ++i5) {
            acc[i5].x += __shfl_xor(acc[i5].x, o);
            acc[i5].y += __shfl_xor(acc[i5].y, o);
            acc[i5].z += __shfl_xor(acc[i5].z, o);
            acc[i5].w += __shfl_xor(acc[i5].w, o);
        }
    }

    // 20-lane store (jp<5): lane (q,jp) writes float4 index q + 4*jp.
    // Static select of acc[jp] (rule #20: no runtime-indexed reg arrays).
    float4 out = acc[0];
    out = (jp == 1) ? acc[1] : out;
    out = (jp == 2) ? acc[2] : out;
    out = (jp == 3) ? acc[3] : out;
    out = (jp == 4) ? acc[4] : out;
    if (jp < 5) {
        const float inv = 1.0f / ls;
        float4* u4 = (float4*)u + (size_t)wv * NF4 + q + 4 * jp;
        *u4 = make_float4(out.x * inv, out.y * inv, out.z * inv, out.w * inv);
    }
}

extern "C" void kernel_launch(void* const* d_in, const int* in_sizes, int n_in,
                              void* d_out, int out_size, void* d_ws, size_t ws_size,
                              hipStream_t stream) {
    const float* h     = (const float*)d_in[0];
    const float* d     = (const float*)d_in[1];
    const float* sigma = (const float*)d_in[2];
    float* u = (float*)d_out;

    const int bs   = in_sizes[1] / T;                 // 16
    const int size = out_size / (bs * DFEAT);         // 4096
    const int tot  = bs * size;                       // 65536

    char* w = (char*)d_ws;
    float*          cls  = (float*)w;          w += (size_t)bs * T * 4;
    float*          cmax = (float*)w;          w += (size_t)bs * 4;
    unsigned short* perm = (unsigned short*)w;

    hipLaunchKernelGGL(prep_kernel, dim3(bs), dim3(64), 0, stream,
                       d, cls, perm, cmax);
    hipLaunchKernelGGL(align_kernel, dim3(tot / 4), dim3(256), 0, stream,
                       h, cls, perm, cmax, sigma, u, size);
}

// Round 16
// 225.494 us; speedup vs baseline: 1.2304x; 1.2304x over previous
//
#include <hip/hip_runtime.h>

#define T      1024
#define DFEAT  80
#define NF4    20       // DFEAT / 4
#define MARGIN 40.0f    // W^2 = d0^2 + MARGIN*sigma^2 -> tail cut at e^-20
#define PAD_B0 16       // index slop for b0's bucket-sorted centers
#define PAD_BN 2        // safety slop for exactly-sorted b>=1

// ---------------------------------------------------------------------------
// prep: one WAVE per batch. f64 shuffle-scan cumsum. Emits value-sorted
// centers cls + permutation perm + exact f32 cmax[b].     [proven r8..r15]
// ---------------------------------------------------------------------------
__global__ __launch_bounds__(64) void prep_kernel(
    const float* __restrict__ d, float* __restrict__ cls,
    unsigned short* __restrict__ perm, float* __restrict__ cmax)
{
    __shared__ int hist[T];
    const int b = blockIdx.x, lane = threadIdx.x;

    const float4* dr4 = (const float4*)(d + (size_t)b * T) + lane * 4;
    float4 a0 = dr4[0], a1 = dr4[1], a2 = dr4[2], a3 = dr4[3];
    float loc[16] = {a0.x,a0.y,a0.z,a0.w, a1.x,a1.y,a1.z,a1.w,
                     a2.x,a2.y,a2.z,a2.w, a3.x,a3.y,a3.z,a3.w};
    double pre[17];
    pre[0] = 0.0;
    #pragma unroll
    for (int i = 0; i < 16; ++i) pre[i + 1] = pre[i] + (double)loc[i];
    const double lsum = pre[16];
    double x = lsum;
    #pragma unroll
    for (int off = 1; off < 64; off <<= 1) {
        double y = __shfl_up(x, off);
        if (lane >= off) x += y;
    }
    const double exclb = x - lsum;        // sum over lanes < lane
    const double total = __shfl(x, 63);

    float val[16];
    #pragma unroll
    for (int i = 0; i < 16; ++i) {
        const int t = lane * 16 + i;
        double cs;
        if (b == 0)      cs = 0.0;        // ref quirk: whole batch-0 row
        else if (t == 0) cs = total;      // roll wraps row total to t=0
        else             cs = exclb + pre[i];
        val[i] = (float)((double)loc[i] * 0.5 + cs);
    }

    if (b > 0) {
        #pragma unroll
        for (int i = 0; i < 16; ++i) {
            const int t = lane * 16 + i;
            const int j = (t == 0) ? (T - 1) : (t - 1);   // rotation = sorted
            cls[b * T + j]  = val[i];
            perm[b * T + j] = (unsigned short)t;
        }
        if (lane == 0) cmax[b] = val[0];                  // t=0 is global max
    } else {
        float mn = val[0], mx = val[0];
        #pragma unroll
        for (int i = 1; i < 16; ++i) { mn = fminf(mn, val[i]); mx = fmaxf(mx, val[i]); }
        #pragma unroll
        for (int off = 32; off > 0; off >>= 1) {
            mn = fminf(mn, __shfl_xor(mn, off));
            mx = fmaxf(mx, __shfl_xor(mx, off));
        }
        if (lane == 0) cmax[0] = mx;
        const float scale = 1023.0f / fmaxf(mx - mn, 1e-20f);
        int bkt[16];
        #pragma unroll
        for (int i = 0; i < 16; ++i)
            bkt[i] = min(1023, max(0, (int)((val[i] - mn) * scale)));
        for (int i = lane; i < T; i += 64) hist[i] = 0;
        __syncthreads();                   // single wave: cheap
        #pragma unroll
        for (int i = 0; i < 16; ++i) atomicAdd(&hist[bkt[i]], 1);
        __syncthreads();
        int hp[17];
        hp[0] = 0;
        #pragma unroll
        for (int i = 0; i < 16; ++i) hp[i + 1] = hp[i] + hist[lane * 16 + i];
        const int hl = hp[16];
        int xs = hl;
        #pragma unroll
        for (int off = 1; off < 64; off <<= 1) {
            int ys = __shfl_up(xs, off);
            if (lane >= off) xs += ys;
        }
        const int base = xs - hl;          // exclusive over lanes
        __syncthreads();
        #pragma unroll
        for (int i = 0; i < 16; ++i) hist[lane * 16 + i] = base + hp[i];
        __syncthreads();
        #pragma unroll
        for (int i = 0; i < 16; ++i) {
            const int pos = atomicAdd(&hist[bkt[i]], 1);
            cls[pos]  = val[i];
            perm[pos] = (unsigned short)(lane * 16 + i);
        }
    }
}

// first index j in [0, T) with a[j] >= x ; returns T if none
__device__ __forceinline__ int lbg(const float* __restrict__ a, float x) {
    int base = 0, len = T;
    while (len > 0) {
        int half = len >> 1;
        if (a[base + half] < x) { base += half + 1; len -= half + 1; }
        else len = half;
    }
    return base;
}

// ---------------------------------------------------------------------------
// align: ONE WAVE per (b,s). j split 16-way (jp) x features 4-way (q, 5
// float4/lane). NAMED accumulators acc0..acc4 — round-15 lesson (rule #20):
// `float4 acc[5]` went to SCRATCH (VGPR=32, 424 MB spill writes, 221 us);
// launch_bounds alone did NOT fix it. No local arrays anywhere.
// Weights in REFERENCE f32 op order: v = -(dd*dd)/tss, w = __expf(v - v0),
// v0 = -(d0*d0)/tss, exact f32 d0.   (round-4 lesson)
// ---------------------------------------------------------------------------
__global__ __launch_bounds__(256, 4) void align_kernel(
    const float* __restrict__ h, const float* __restrict__ cls,
    const unsigned short* __restrict__ perm, const float* __restrict__ cmax,
    const float* __restrict__ sigma, float* __restrict__ u, int size)
{
    const int wv   = (blockIdx.x << 2) | (threadIdx.x >> 6);  // slin = b*size+s
    const int lane = threadIdx.x & 63;
    const int jp   = lane & 15;          // j-parallel lane
    const int q    = lane >> 4;          // feature quad: float4 idx q + 4*i5
    const int b    = wv / size;
    const int s    = wv - b * size;

    const float sg  = sigma[0];
    const float tss = 2.0f * sg * sg;
    const float ts  = (float)s + 1.5f;

    const float* a = cls + (size_t)b * T;

    // window (all lanes redundantly; identical addresses -> broadcast loads)
    float d0; int pad;
    if (b == 0) {
        d0 = fabsf(ts - cmax[0]);        // ts > all centers -> nearest = cmax
        pad = PAD_B0;
    } else {
        const int ins = lbg(a, ts);
        d0 = 1e30f;
        if (ins < T) d0 = fminf(d0, fabsf(a[ins] - ts));
        if (ins > 0) d0 = fminf(d0, fabsf(ts - a[ins - 1]));
        pad = PAD_BN;
    }
    const float Ws  = sqrtf(fmaf(sg * sg, MARGIN, d0 * d0));
    const int   jlo = max(0, lbg(a, ts - Ws) - pad);
    const int   jhi = min(T, lbg(a, ts + Ws) + pad);
    const float v0  = -(d0 * d0) / tss;  // f32 max score, ref rounding

    const unsigned short* pb = perm + (size_t)b * T;
    const float4* hb4 = (const float4*)(h + (size_t)b * T * DFEAT);

    float4 acc0 = make_float4(0.f, 0.f, 0.f, 0.f);
    float4 acc1 = make_float4(0.f, 0.f, 0.f, 0.f);
    float4 acc2 = make_float4(0.f, 0.f, 0.f, 0.f);
    float4 acc3 = make_float4(0.f, 0.f, 0.f, 0.f);
    float4 acc4 = make_float4(0.f, 0.f, 0.f, 0.f);
    float ls = 0.f;

    for (int j = jlo + jp; j < jhi; j += 16) {
        const float cv = a[j];
        const float dd = ts - cv;
        const float v  = -(dd * dd) / tss;           // ref op order
        const float w  = __expf(v - v0);
        ls += w;
        const int row = pb[j];
        const float4* hr = hb4 + (size_t)row * NF4 + q;
        const float4 hv0 = hr[0];
        const float4 hv1 = hr[4];
        const float4 hv2 = hr[8];
        const float4 hv3 = hr[12];
        const float4 hv4 = hr[16];
        acc0.x += w * hv0.x; acc0.y += w * hv0.y; acc0.z += w * hv0.z; acc0.w += w * hv0.w;
        acc1.x += w * hv1.x; acc1.y += w * hv1.y; acc1.z += w * hv1.z; acc1.w += w * hv1.w;
        acc2.x += w * hv2.x; acc2.y += w * hv2.y; acc2.z += w * hv2.z; acc2.w += w * hv2.w;
        acc3.x += w * hv3.x; acc3.y += w * hv3.y; acc3.z += w * hv3.z; acc3.w += w * hv3.w;
        acc4.x += w * hv4.x; acc4.y += w * hv4.y; acc4.z += w * hv4.z; acc4.w += w * hv4.w;
    }

    // reduce over the 16 jp lanes (xor 1,2,4,8 stays within the q-group)
    #pragma unroll
    for (int o = 1; o <= 8; o <<= 1) {
        ls += __shfl_xor(ls, o);
        acc0.x += __shfl_xor(acc0.x, o); acc0.y += __shfl_xor(acc0.y, o);
        acc0.z += __shfl_xor(acc0.z, o); acc0.w += __shfl_xor(acc0.w, o);
        acc1.x += __shfl_xor(acc1.x, o); acc1.y += __shfl_xor(acc1.y, o);
        acc1.z += __shfl_xor(acc1.z, o); acc1.w += __shfl_xor(acc1.w, o);
        acc2.x += __shfl_xor(acc2.x, o); acc2.y += __shfl_xor(acc2.y, o);
        acc2.z += __shfl_xor(acc2.z, o); acc2.w += __shfl_xor(acc2.w, o);
        acc3.x += __shfl_xor(acc3.x, o); acc3.y += __shfl_xor(acc3.y, o);
        acc3.z += __shfl_xor(acc3.z, o); acc3.w += __shfl_xor(acc3.w, o);
        acc4.x += __shfl_xor(acc4.x, o); acc4.y += __shfl_xor(acc4.y, o);
        acc4.z += __shfl_xor(acc4.z, o); acc4.w += __shfl_xor(acc4.w, o);
    }

    // 20-lane store (jp<5): lane (q,jp) writes float4 index q + 4*jp.
    // Fully-named static select (rule #20: no runtime-indexed reg arrays).
    float4 out = acc0;
    out = (jp == 1) ? acc1 : out;
    out = (jp == 2) ? acc2 : out;
    out = (jp == 3) ? acc3 : out;
    out = (jp == 4) ? acc4 : out;
    if (jp < 5) {
        const float inv = 1.0f / ls;
        float4* u4 = (float4*)u + (size_t)wv * NF4 + q + 4 * jp;
        *u4 = make_float4(out.x * inv, out.y * inv, out.z * inv, out.w * inv);
    }
}

extern "C" void kernel_launch(void* const* d_in, const int* in_sizes, int n_in,
                              void* d_out, int out_size, void* d_ws, size_t ws_size,
                              hipStream_t stream) {
    const float* h     = (const float*)d_in[0];
    const float* d     = (const float*)d_in[1];
    const float* sigma = (const float*)d_in[2];
    float* u = (float*)d_out;

    const int bs   = in_sizes[1] / T;                 // 16
    const int size = out_size / (bs * DFEAT);         // 4096
    const int tot  = bs * size;                       // 65536

    char* w = (char*)d_ws;
    float*          cls  = (float*)w;          w += (size_t)bs * T * 4;
    float*          cmax = (float*)w;          w += (size_t)bs * 4;
    unsigned short* perm = (unsigned short*)w;

    hipLaunchKernelGGL(prep_kernel, dim3(bs), dim3(64), 0, stream,
                       d, cls, perm, cmax);
    hipLaunchKernelGGL(align_kernel, dim3(tot / 4), dim3(256), 0, stream,
                       h, cls, perm, cmax, sigma, u, size);
}